// Round 9
// baseline (534.709 us; speedup 1.0000x reference)
//
#include <hip/hip_runtime.h>
#include <hip/hip_bf16.h>

#define LL 512
#define HH 128
#define NBATCH 2
#define NT 32

typedef float f32x4 __attribute__((ext_vector_type(4)));
typedef short s16x8 __attribute__((ext_vector_type(8)));
typedef unsigned int u32x4 __attribute__((ext_vector_type(4)));

__device__ __forceinline__ unsigned short f2bfu(float f){
  __hip_bfloat16 h = __float2bfloat16(f);
  return __builtin_bit_cast(unsigned short, h);
}
// max of two packed-bf16 words (both bf16-valued -> exact; max commutes with RN)
__device__ __forceinline__ unsigned int bmax2(unsigned int a, unsigned int b){
  float lo = fmaxf(__uint_as_float(a << 16), __uint_as_float(b << 16));
  float hi = fmaxf(__uint_as_float(a & 0xFFFF0000u), __uint_as_float(b & 0xFFFF0000u));
  return __float_as_uint(hi) | (__float_as_uint(lo) >> 16);
}
__device__ __forceinline__ u32x4 bmax4(u32x4 a, u32x4 b){
  u32x4 r; r[0]=bmax2(a[0],b[0]); r[1]=bmax2(a[1],b[1]);
  r[2]=bmax2(a[2],b[2]); r[3]=bmax2(a[3],b[3]); return r;
}
__device__ __forceinline__ float gelu_f(float v){
  float inner = v * fmaf(0.044715f, v*v, 1.0f);
  float e = __expf(1.5957691216f * inner);
  float s = __fdividef(1.0f, e + 1.0f);
  return fmaf(-v, s, v);
}
__device__ __forceinline__ f32x4 gelu4(f32x4 v){
  f32x4 r;
  #pragma unroll
  for (int i=0;i<4;++i) r[i] = gelu_f(v[i]);
  return r;
}

// ---- prep1: t1/t2 (1024) | pfx/sfx/tilemax/ST (64) | Wcb (8) ----
__global__ void prep_kernel(const float* __restrict__ x, const float* __restrict__ y,
                            const float* __restrict__ W, const float* __restrict__ bias,
                            float* __restrict__ t1, float* __restrict__ t2,
                            float* __restrict__ tilemax, short* __restrict__ pfxT,
                            short* __restrict__ sfxT, short* __restrict__ ST,
                            short* __restrict__ Wcb){
  int blk = blockIdx.x, tid = threadIdx.x;
  if (blk < NBATCH*LL){
    int b = blk >> 9, ll = blk & (LL-1);
    __shared__ float xs[HH], ys[HH];
    size_t base = ((size_t)b*LL + ll)*HH;
    if (tid < HH) xs[tid] = x[base + tid];
    else          ys[tid-HH] = y[base + tid - HH];
    __syncthreads();
    int role = tid >> 7, g = tid & (HH-1);
    const float4* wr = (const float4*)(W + (size_t)g*384 + role*HH);
    const float4* vs = (const float4*)(role ? ys : xs);
    float sA = 0.f, sB = 0.f;
    #pragma unroll
    for (int q=0;q<32;q+=2){
      float4 a = vs[q],   w1 = wr[q];
      sA = fmaf(a.x,w1.x, fmaf(a.y,w1.y, fmaf(a.z,w1.z, fmaf(a.w,w1.w, sA))));
      float4 c = vs[q+1], w2 = wr[q+1];
      sB = fmaf(c.x,w2.x, fmaf(c.y,w2.y, fmaf(c.z,w2.z, fmaf(c.w,w2.w, sB))));
    }
    float s = sA + sB;
    if (role == 0) t1[base + g] = s + bias[g];
    else           t2[base + g] = s;
  } else if (blk < NBATCH*LL + NBATCH*NT){
    int e = blk - NBATCH*LL;      // (b, tile)
    int b = e >> 5, t = e & 31;
    int role = tid >> 7, h = tid & (HH-1);
    const float* xp = x + ((size_t)b*LL + t*16)*HH + h;
    float v[16];
    #pragma unroll
    for (int r=0;r<16;++r) v[r] = xp[r*HH];
    const size_t rowb = ((size_t)(b*NT + t))*16;
    if (role == 0){
      float run = -INFINITY;
      #pragma unroll
      for (int r=0;r<16;++r){ run = fmaxf(run, v[r]);
        pfxT[(rowb + r)*HH + h] = (short)f2bfu(run); }
      tilemax[((size_t)(b*NT + t))*HH + h] = run;
    } else {
      float run = -INFINITY;
      #pragma unroll
      for (int r=15;r>=0;--r){ run = fmaxf(run, v[r]);
        sfxT[(rowb + r)*HH + h] = (short)f2bfu(run); }
      // sparse-table levels 0..3
      const size_t stb = ((size_t)(b*NT + t))*4*16;
      float cur[16];
      #pragma unroll
      for (int r=0;r<16;++r){ cur[r] = v[r];
        ST[(stb + r)*HH + h] = (short)f2bfu(v[r]); }
      #pragma unroll
      for (int k=1;k<4;++k){
        int step = 1 << (k-1);
        float nw[16];
        #pragma unroll
        for (int r=0;r<16;++r) nw[r] = fmaxf(cur[r], cur[min(r+step,15)]);
        #pragma unroll
        for (int r=0;r<16;++r){
          ST[(stb + k*16 + r)*HH + h] = (short)f2bfu(nw[r]);
          cur[r] = nw[r];
        }
      }
    }
  } else {
    int e0 = ((blk - (NBATCH*LL + NBATCH*NT))*256 + tid)*8;
    #pragma unroll
    for (int q=0;q<8;++q){
      int e = e0 + q; int g = e >> 7, h = e & (HH-1);
      Wcb[e] = (short)f2bfu(W[(size_t)g*384 + 256 + h]);
    }
  }
}

// ---- prep2: TMR[b][t0][t1][h] = max(tilemax[t0+1..t1-1]) (exclusive range) ----
__global__ void tmr_kernel(const float* __restrict__ tilemax, short* __restrict__ TMR){
  int blk = blockIdx.x;            // b*NT + t0
  int b = blk >> 5, t0 = blk & 31;
  int h = threadIdx.x;             // 128 threads
  float tm[NT];
  #pragma unroll
  for (int t=0;t<NT;++t) tm[t] = tilemax[((size_t)(b*NT)+t)*HH + h];
  const size_t rb = ((size_t)(b*NT)+t0)*NT;
  float run = -INFINITY;
  for (int tb=t0+1; tb<NT; ++tb){
    TMR[(rb + tb)*HH + h] = (short)f2bfu(run);
    run = fmaxf(run, tm[tb]);
  }
  run = -INFINITY;
  for (int tb=t0-1; tb>=0; --tb){
    TMR[(rb + tb)*HH + h] = (short)f2bfu(run);
    run = fmaxf(run, tm[tb]);
  }
}

// ---- main: one block per output ROW (b,i). Wave w owns j-tiles [8w,8w+8);
//      acc bounced via wave-private LDS (16B-granule XOR swizzle);
//      stores = plain 1 KB contiguous (L2 write-combines full lines). ----
__global__ __launch_bounds__(256, 5) void ctx_kernel(
    const float* __restrict__ t1, const float* __restrict__ t2,
    const short* __restrict__ pfxT, const short* __restrict__ sfxT,
    const short* __restrict__ ST, const short* __restrict__ TMR,
    const short* __restrict__ Wcb, float* __restrict__ out)
{
  __shared__ __align__(16) float bounce[4][16*HH];   // 32 KB total
  const int tid = threadIdx.x;
  const int i = blockIdx.x, b = blockIdx.y;
  const int ti = i >> 4, ri = i & 15;
  const int w = tid >> 6, l = tid & 63, l16 = l & 15, lhi = l >> 4;
  const size_t bL = (size_t)b*LL;
  const size_t bNT = (size_t)b*NT;
  float* Bw = bounce[w];

  const int gs = (l & 31) * 4;                       // store-stage g (words)
  const f32x4 t1v = *(const f32x4*)(t1 + (bL + i)*HH + gs);

  u32x4 sfxo[4], pfxo[4];
  #pragma unroll
  for (int kb=0;kb<4;++kb){
    int h0 = kb*32 + lhi*8;
    sfxo[kb] = *(const u32x4*)&sfxT[((bNT + ti)*16 + ri)*HH + h0];
    pfxo[kb] = *(const u32x4*)&pfxT[((bNT + ti)*16 + ri)*HH + h0];
  }

  #pragma unroll
  for (int tt=0; tt<8; ++tt){
    const int t = w*8 + tt;
    u32x4 fr[4];
    if (t > ti){
      #pragma unroll
      for (int kb=0;kb<4;++kb){
        int h0 = kb*32 + lhi*8;
        u32x4 tm = *(const u32x4*)&TMR[((bNT + ti)*NT + t)*HH + h0];
        u32x4 sd = *(const u32x4*)&pfxT[((bNT + t)*16 + l16)*HH + h0];
        fr[kb] = bmax4(sd, bmax4(sfxo[kb], tm));
      }
    } else if (t < ti){
      #pragma unroll
      for (int kb=0;kb<4;++kb){
        int h0 = kb*32 + lhi*8;
        u32x4 tm = *(const u32x4*)&TMR[((bNT + ti)*NT + t)*HH + h0];
        u32x4 sd = *(const u32x4*)&sfxT[((bNT + t)*16 + l16)*HH + h0];
        fr[kb] = bmax4(sd, bmax4(pfxo[kb], tm));
      }
    } else {
      int a = min(ri, l16), bb = max(ri, l16);
      int len = bb - a + 1;
      int k = 31 - __clz(len); if (k > 3) k = 3;
      int r2 = bb + 1 - (1 << k);
      #pragma unroll
      for (int kb=0;kb<4;++kb){
        int h0 = kb*32 + lhi*8;
        u32x4 ua = *(const u32x4*)&ST[(((bNT + ti)*4 + k)*16 + a )*HH + h0];
        u32x4 ub = *(const u32x4*)&ST[(((bNT + ti)*4 + k)*16 + r2)*HH + h0];
        fr[kb] = bmax4(ua, ub);
      }
    }

    // GEMM this j-tile: D[g, j=l16], park in wave-private LDS.
    // layout: word = j*128 + (gword ^ ((j&7)<<2))  -- 16B-granule XOR swizzle
    #pragma unroll
    for (int nt=0; nt<8; ++nt){
      s16x8 wcf[4];
      #pragma unroll
      for (int kb=0;kb<4;++kb)
        wcf[kb] = *(const s16x8*)(Wcb + (size_t)(nt*16 + l16)*HH + kb*32 + lhi*8);
      f32x4 acc = (f32x4){0.f,0.f,0.f,0.f};
      #pragma unroll
      for (int kb=0;kb<4;++kb)
        acc = __builtin_amdgcn_mfma_f32_16x16x32_bf16(wcf[kb],
                __builtin_bit_cast(s16x8, fr[kb]), acc, 0, 0, 0);
      int gw = (nt*16 + lhi*4) ^ ((l16 & 7) << 2);
      *(f32x4*)&Bw[l16*HH + gw] = acc;
    }
    asm volatile("" ::: "memory");

    // drain: 8 x 1 KB contiguous plain stores (rows ascending; full L2 lines)
    #pragma unroll
    for (int m=0; m<8; ++m){
      const int j = m*2 + (l >> 5);
      const int gr = gs ^ ((j & 7) << 2);
      f32x4 v = *(const f32x4*)&Bw[j*HH + gr];
      const int row = t*16 + j;
      f32x4 t2v = *(const f32x4*)(t2 + (bL + row)*HH + gs);
      f32x4 o = gelu4(v + t1v + t2v);
      *(f32x4*)(out + ((bL + i)*LL + row)*HH + gs) = o;
    }
    asm volatile("" ::: "memory");
  }
}

extern "C" void kernel_launch(void* const* d_in, const int* in_sizes, int n_in,
                              void* d_out, int out_size, void* d_ws, size_t ws_size,
                              hipStream_t stream) {
  const float* x    = (const float*)d_in[0];
  const float* y    = (const float*)d_in[1];
  const float* W    = (const float*)d_in[2];
  const float* bias = (const float*)d_in[3];
  float* out = (float*)d_out;

  float* t1      = (float*)d_ws;                      // B*L*H f32
  float* t2      = t1 + (size_t)NBATCH*LL*HH;         // B*L*H f32
  float* tilemax = t2 + (size_t)NBATCH*LL*HH;         // B*NT*H f32
  short* Wcb  = (short*)(tilemax + (size_t)NBATCH*NT*HH);  // 128*128 bf16
  short* pfxT = Wcb  + (size_t)HH*HH;                 // B*NT*16*H
  short* sfxT = pfxT + (size_t)NBATCH*NT*16*HH;       // B*NT*16*H
  short* ST   = sfxT + (size_t)NBATCH*NT*16*HH;       // B*NT*4*16*H
  short* TMR  = ST   + (size_t)NBATCH*NT*4*16*HH;     // B*NT*NT*H

  prep_kernel<<<NBATCH*LL + NBATCH*NT + 8, 256, 0, stream>>>(
      x, y, W, bias, t1, t2, tilemax, pfxT, sfxT, ST, Wcb);
  tmr_kernel<<<NBATCH*NT, HH, 0, stream>>>(tilemax, TMR);
  ctx_kernel<<<dim3(LL, NBATCH), 256, 0, stream>>>(
      t1, t2, pfxT, sfxT, ST, TMR, Wcb, out);
}

// Round 10
// 156.993 us; speedup vs baseline: 3.4059x; 3.4059x over previous
//
#include <hip/hip_runtime.h>
#include <hip/hip_bf16.h>

#define LL 512
#define HH 128
#define NBATCH 2
#define NT 32

typedef float f32x4 __attribute__((ext_vector_type(4)));
typedef short s16x8 __attribute__((ext_vector_type(8)));
typedef unsigned int u32x4 __attribute__((ext_vector_type(4)));

__device__ __forceinline__ unsigned short f2bfu(float f){
  __hip_bfloat16 h = __float2bfloat16(f);
  return __builtin_bit_cast(unsigned short, h);
}
__device__ __forceinline__ unsigned int bmax2(unsigned int a, unsigned int b){
  float lo = fmaxf(__uint_as_float(a << 16), __uint_as_float(b << 16));
  float hi = fmaxf(__uint_as_float(a & 0xFFFF0000u), __uint_as_float(b & 0xFFFF0000u));
  return __float_as_uint(hi) | (__float_as_uint(lo) >> 16);
}
__device__ __forceinline__ u32x4 bmax4(u32x4 a, u32x4 b){
  u32x4 r; r[0]=bmax2(a[0],b[0]); r[1]=bmax2(a[1],b[1]);
  r[2]=bmax2(a[2],b[2]); r[3]=bmax2(a[3],b[3]); return r;
}
__device__ __forceinline__ float gelu_f(float v){
  float inner = v * fmaf(0.044715f, v*v, 1.0f);
  float e = __expf(1.5957691216f * inner);
  float s = __fdividef(1.0f, e + 1.0f);
  return fmaf(-v, s, v);
}
__device__ __forceinline__ f32x4 gelu4(f32x4 v){
  f32x4 r;
  #pragma unroll
  for (int i=0;i<4;++i) r[i] = gelu_f(v[i]);
  return r;
}

// ---- prep1: t1 f32 / t2b bf16 (1024) | pfx/sfx/tilemax/ST (64) | Wcb (8) ----
__global__ void prep_kernel(const float* __restrict__ x, const float* __restrict__ y,
                            const float* __restrict__ W, const float* __restrict__ bias,
                            float* __restrict__ t1, unsigned short* __restrict__ t2b,
                            float* __restrict__ tilemax, short* __restrict__ pfxT,
                            short* __restrict__ sfxT, short* __restrict__ ST,
                            short* __restrict__ Wcb){
  int blk = blockIdx.x, tid = threadIdx.x;
  if (blk < NBATCH*LL){
    int b = blk >> 9, ll = blk & (LL-1);
    __shared__ float xs[HH], ys[HH];
    size_t base = ((size_t)b*LL + ll)*HH;
    if (tid < HH) xs[tid] = x[base + tid];
    else          ys[tid-HH] = y[base + tid - HH];
    __syncthreads();
    int role = tid >> 7, g = tid & (HH-1);
    const float4* wr = (const float4*)(W + (size_t)g*384 + role*HH);
    const float4* vs = (const float4*)(role ? ys : xs);
    float sA = 0.f, sB = 0.f;
    #pragma unroll
    for (int q=0;q<32;q+=2){
      float4 a = vs[q],   w1 = wr[q];
      sA = fmaf(a.x,w1.x, fmaf(a.y,w1.y, fmaf(a.z,w1.z, fmaf(a.w,w1.w, sA))));
      float4 c = vs[q+1], w2 = wr[q+1];
      sB = fmaf(c.x,w2.x, fmaf(c.y,w2.y, fmaf(c.z,w2.z, fmaf(c.w,w2.w, sB))));
    }
    float s = sA + sB;
    if (role == 0) t1[base + g] = s + bias[g];
    else           t2b[base + g] = f2bfu(s);
  } else if (blk < NBATCH*LL + NBATCH*NT){
    int e = blk - NBATCH*LL;      // (b, tile)
    int b = e >> 5, t = e & 31;
    int role = tid >> 7, h = tid & (HH-1);
    const float* xp = x + ((size_t)b*LL + t*16)*HH + h;
    float v[16];
    #pragma unroll
    for (int r=0;r<16;++r) v[r] = xp[r*HH];
    const size_t rowb = ((size_t)(b*NT + t))*16;
    if (role == 0){
      float run = -INFINITY;
      #pragma unroll
      for (int r=0;r<16;++r){ run = fmaxf(run, v[r]);
        pfxT[(rowb + r)*HH + h] = (short)f2bfu(run); }
      tilemax[((size_t)(b*NT + t))*HH + h] = run;
    } else {
      float run = -INFINITY;
      #pragma unroll
      for (int r=15;r>=0;--r){ run = fmaxf(run, v[r]);
        sfxT[(rowb + r)*HH + h] = (short)f2bfu(run); }
      const size_t stb = ((size_t)(b*NT + t))*4*16;
      float cur[16];
      #pragma unroll
      for (int r=0;r<16;++r){ cur[r] = v[r];
        ST[(stb + r)*HH + h] = (short)f2bfu(v[r]); }
      #pragma unroll
      for (int k=1;k<4;++k){
        int step = 1 << (k-1);
        float nw[16];
        #pragma unroll
        for (int r=0;r<16;++r) nw[r] = fmaxf(cur[r], cur[min(r+step,15)]);
        #pragma unroll
        for (int r=0;r<16;++r){
          ST[(stb + k*16 + r)*HH + h] = (short)f2bfu(nw[r]);
          cur[r] = nw[r];
        }
      }
    }
  } else {
    int e0 = ((blk - (NBATCH*LL + NBATCH*NT))*256 + tid)*8;
    #pragma unroll
    for (int q=0;q<8;++q){
      int e = e0 + q; int g = e >> 7, h = e & (HH-1);
      Wcb[e] = (short)f2bfu(W[(size_t)g*384 + 256 + h]);
    }
  }
}

// ---- prep2: TMR[b][t0][t1][h] = max(tilemax[t0+1..t1-1]) (exclusive range) ----
__global__ void tmr_kernel(const float* __restrict__ tilemax, short* __restrict__ TMR){
  int blk = blockIdx.x;            // b*NT + t0
  int b = blk >> 5, t0 = blk & 31;
  int h = threadIdx.x;             // 128 threads
  float tm[NT];
  #pragma unroll
  for (int t=0;t<NT;++t) tm[t] = tilemax[((size_t)(b*NT)+t)*HH + h];
  const size_t rb = ((size_t)(b*NT)+t0)*NT;
  float run = -INFINITY;
  for (int tb=t0+1; tb<NT; ++tb){
    TMR[(rb + tb)*HH + h] = (short)f2bfu(run);
    run = fmaxf(run, tm[tb]);
  }
  run = -INFINITY;
  for (int tb=t0-1; tb>=0; --tb){
    TMR[(rb + tb)*HH + h] = (short)f2bfu(run);
    run = fmaxf(run, tm[tb]);
  }
}

// ---- main: block = (b, 4 rows of one 16-tile); 512 threads / 8 waves.
//      wave = (row, j-half). Wc frags + own-row scans live in REGISTERS;
//      hot loop reads only small per-j-tile tables + prefetched bf16 t2. ----
__global__ __launch_bounds__(512, 2) void ctx_kernel(
    const float* __restrict__ t1, const unsigned short* __restrict__ t2b,
    const short* __restrict__ pfxT, const short* __restrict__ sfxT,
    const short* __restrict__ ST, const short* __restrict__ TMR,
    const short* __restrict__ Wcb, float* __restrict__ out)
{
  __shared__ __align__(16) float bounce[8][16*HH];   // 64 KB
  const int tid = threadIdx.x;
  const int b = blockIdx.y;
  const int w = tid >> 6, l = tid & 63, l16 = l & 15, lhi = l >> 4;
  const int row_i = blockIdx.x*4 + (w >> 1);
  const int jhalf = w & 1;
  const int ti = row_i >> 4, ri = row_i & 15;
  const size_t bL = (size_t)b*LL;
  const size_t bNT = (size_t)b*NT;
  float* Bw = bounce[w];

  // loop-invariant registers
  s16x8 wcf[8][4];
  #pragma unroll
  for (int nt=0; nt<8; ++nt)
    #pragma unroll
    for (int kb=0; kb<4; ++kb)
      wcf[nt][kb] = *(const s16x8*)(Wcb + (size_t)(nt*16 + l16)*HH + kb*32 + lhi*8);

  u32x4 sfxo[4], pfxo[4];
  #pragma unroll
  for (int kb=0; kb<4; ++kb){
    int h0 = kb*32 + lhi*8;
    sfxo[kb] = *(const u32x4*)&sfxT[((bNT + ti)*16 + ri)*HH + h0];
    pfxo[kb] = *(const u32x4*)&pfxT[((bNT + ti)*16 + ri)*HH + h0];
  }
  const int gs = (l & 31) * 4;
  const f32x4 t1v = *(const f32x4*)(t1 + (bL + row_i)*HH + gs);
  float* orow = out + (bL + row_i)*LL*HH;

  for (int jt=0; jt<16; ++jt){
    const int t = jhalf*16 + jt;

    // ---- build fragment (the only hot-loop global table reads) ----
    u32x4 fr[4];
    if (t > ti){
      #pragma unroll
      for (int kb=0;kb<4;++kb){
        int h0 = kb*32 + lhi*8;
        u32x4 tm = *(const u32x4*)&TMR[((bNT + ti)*NT + t)*HH + h0];
        u32x4 sd = *(const u32x4*)&pfxT[((bNT + t)*16 + l16)*HH + h0];
        fr[kb] = bmax4(sd, bmax4(sfxo[kb], tm));
      }
    } else if (t < ti){
      #pragma unroll
      for (int kb=0;kb<4;++kb){
        int h0 = kb*32 + lhi*8;
        u32x4 tm = *(const u32x4*)&TMR[((bNT + ti)*NT + t)*HH + h0];
        u32x4 sd = *(const u32x4*)&sfxT[((bNT + t)*16 + l16)*HH + h0];
        fr[kb] = bmax4(sd, bmax4(pfxo[kb], tm));
      }
    } else {
      int a = min(ri, l16), bb = max(ri, l16);
      int len = bb - a + 1;
      int k = 31 - __clz(len); if (k > 3) k = 3;
      int r2 = bb + 1 - (1 << k);
      #pragma unroll
      for (int kb=0;kb<4;++kb){
        int h0 = kb*32 + lhi*8;
        u32x4 ua = *(const u32x4*)&ST[(((bNT + ti)*4 + k)*16 + a )*HH + h0];
        u32x4 ub = *(const u32x4*)&ST[(((bNT + ti)*4 + k)*16 + r2)*HH + h0];
        fr[kb] = bmax4(ua, ub);
      }
    }

    // ---- prefetch t2 (bf16) for the drain; consumed after MFMA ----
    uint2 t2p[8];
    #pragma unroll
    for (int m=0;m<8;++m){
      const int j = m*2 + (l >> 5);
      t2p[m] = *(const uint2*)(t2b + (bL + t*16 + j)*HH + gs);
    }

    // ---- GEMM: 8 nt x 4 kb MFMA, park in wave-private LDS ----
    #pragma unroll
    for (int nt=0; nt<8; ++nt){
      f32x4 acc = (f32x4){0.f,0.f,0.f,0.f};
      #pragma unroll
      for (int kb=0;kb<4;++kb)
        acc = __builtin_amdgcn_mfma_f32_16x16x32_bf16(wcf[nt][kb],
                __builtin_bit_cast(s16x8, fr[kb]), acc, 0, 0, 0);
      int gw = (nt*16 + lhi*4) ^ ((l16 & 7) << 2);
      *(f32x4*)&Bw[l16*HH + gw] = acc;
    }
    asm volatile("" ::: "memory");

    // ---- drain: 8 x 1 KB contiguous plain stores, zero global reads ----
    #pragma unroll
    for (int m=0; m<8; ++m){
      const int j = m*2 + (l >> 5);
      const int gr = gs ^ ((j & 7) << 2);
      f32x4 v = *(const f32x4*)&Bw[j*HH + gr];
      f32x4 t2v;
      t2v[0] = __uint_as_float(t2p[m].x << 16);
      t2v[1] = __uint_as_float(t2p[m].x & 0xFFFF0000u);
      t2v[2] = __uint_as_float(t2p[m].y << 16);
      t2v[3] = __uint_as_float(t2p[m].y & 0xFFFF0000u);
      f32x4 o = gelu4(v + t1v + t2v);
      *(f32x4*)(orow + (size_t)(t*16 + j)*HH + gs) = o;
    }
    asm volatile("" ::: "memory");
  }
}

extern "C" void kernel_launch(void* const* d_in, const int* in_sizes, int n_in,
                              void* d_out, int out_size, void* d_ws, size_t ws_size,
                              hipStream_t stream) {
  const float* x    = (const float*)d_in[0];
  const float* y    = (const float*)d_in[1];
  const float* W    = (const float*)d_in[2];
  const float* bias = (const float*)d_in[3];
  float* out = (float*)d_out;

  float* t1      = (float*)d_ws;                            // B*L*H f32
  unsigned short* t2b = (unsigned short*)(t1 + (size_t)NBATCH*LL*HH); // B*L*H bf16
  float* tilemax = (float*)(t2b + (size_t)NBATCH*LL*HH);    // B*NT*H f32
  short* Wcb  = (short*)(tilemax + (size_t)NBATCH*NT*HH);   // 128*128 bf16
  short* pfxT = Wcb  + (size_t)HH*HH;                       // B*NT*16*H
  short* sfxT = pfxT + (size_t)NBATCH*NT*16*HH;             // B*NT*16*H
  short* ST   = sfxT + (size_t)NBATCH*NT*16*HH;             // B*NT*4*16*H
  short* TMR  = ST   + (size_t)NBATCH*NT*4*16*HH;           // B*NT*NT*H

  prep_kernel<<<NBATCH*LL + NBATCH*NT + 8, 256, 0, stream>>>(
      x, y, W, bias, t1, t2b, tilemax, pfxT, sfxT, ST, Wcb);
  tmr_kernel<<<NBATCH*NT, HH, 0, stream>>>(tilemax, TMR);
  ctx_kernel<<<dim3(LL/4, NBATCH), 512, 0, stream>>>(
      t1, t2b, pfxT, sfxT, ST, TMR, Wcb, out);
}